// Round 11
// baseline (24.431 us; speedup 1.0000x reference)
//
#include <hip/hip_runtime.h>
#include <math.h>

#define BB 512
#define LL 4096
#define MAXLAG 20
#define NLAGS 41
#define TAU 0.05f
#define NT 1024
#define CHUNK 4

// Plain LDS layout with zero guards: element i (i in [-32, 4160-32)) at lds_p[32 + i].
// All lag-window float4 reads are at 16 B lane stride -> lanes 0..7 cover all 32
// banks -> conflict-free for ds_read_b128 regardless of the (aligned) base offset.

// ---- DPP adds ----
template<int CTRL, int RM, int BM, bool BC>
__device__ __forceinline__ float dpp_add(float x) {
    const int t = __builtin_amdgcn_update_dpp(0, __float_as_int(x), CTRL, RM, BM, BC);
    return x + __int_as_float(t);
}
// full 64-lane sum; result in lane 63
__device__ __forceinline__ float wave_sum63(float x) {
    x = dpp_add<0x111, 0xf, 0xf, true >(x);  // row_shr:1
    x = dpp_add<0x112, 0xf, 0xf, true >(x);  // row_shr:2
    x = dpp_add<0x114, 0xf, 0xf, true >(x);  // row_shr:4
    x = dpp_add<0x118, 0xf, 0xf, true >(x);  // row_shr:8
    x = dpp_add<0x142, 0xa, 0xf, false>(x);  // row_bcast:15
    x = dpp_add<0x143, 0xc, 0xf, false>(x);  // row_bcast:31 -> lane63 total
    return x;
}
// 16-lane row sum; result in lane 15 of each row
__device__ __forceinline__ float row_sum15(float x) {
    x = dpp_add<0x111, 0xf, 0xf, true >(x);
    x = dpp_add<0x112, 0xf, 0xf, true >(x);
    x = dpp_add<0x114, 0xf, 0xf, true >(x);
    x = dpp_add<0x118, 0xf, 0xf, true >(x);
    return x;
}

struct SmemT {
    float redPG[64][NLAGS];       // 64 row-partials (16-lane groups) per lag
    float edges[10][MAXLAG + 1];  // 0:prefP 1:prefPP 2:prefG 3:prefGG (4 unused)
                                  // 5:sufP  6:sufPP  7:sufG  8:sufGG  (9 unused)
    float wsums[16][4];
    float l1part[64];
    float best_pcc, zero_pcc, pen;
    int best_il;
};

// one lag group: lags L0 .. L0+G-1 (L0 % 4 == 0); computes only spg
template<int L0, int G>
__device__ __forceinline__ void lag_group(const float* __restrict__ lds_p,
                                          const float (&gr)[CHUNK],
                                          SmemT& sm, int tid, bool isTail) {
    constexpr int NW4 = (G - 1 + CHUNK + 3) / 4;   // G=8 -> 3 float4, G=1 -> 1
    float pw[NW4 * 4];
    const float* base = lds_p + 32 + 4 * tid + L0;  // 16B-aligned (L0 % 4 == 0)
    #pragma unroll
    for (int k = 0; k < NW4; ++k) {
        const float4 w = *(const float4*)(base + 4 * k);
        pw[4 * k + 0] = w.x; pw[4 * k + 1] = w.y;
        pw[4 * k + 2] = w.z; pw[4 * k + 3] = w.w;
    }
    #pragma unroll
    for (int dl = 0; dl < G; ++dl) {
        float s0 = fmaf(pw[dl],     gr[0], pw[dl + 2] * gr[2]);
        float s1 = fmaf(pw[dl + 1], gr[1], pw[dl + 3] * gr[3]);
        const float spg = row_sum15(s0 + s1);
        if (isTail) sm.redPG[tid >> 4][L0 + MAXLAG + dl] = spg;
    }
}

__global__ __launch_bounds__(NT, 8) void lagloss_kernel(const float* __restrict__ pred,
                                                        const float* __restrict__ gt,
                                                        float4* __restrict__ ws) {
    __shared__ float lds_p[4160];
    __shared__ SmemT sm;

    const int b = blockIdx.x;
    const int tid = threadIdx.x;
    const int wid = tid >> 6;
    const int lane = tid & 63;
    const float* __restrict__ prow = pred + (size_t)b * LL;
    const float* __restrict__ grow = gt + (size_t)b * LL;

    // ---- zero guards: elements [-32,0) and [4096,4128) ----
    if (tid < 16) {
        const int fi = (tid < 8) ? 4 * tid : 4128 + 4 * (tid - 8);
        *(float4*)&lds_p[fi] = float4{0.f, 0.f, 0.f, 0.f};
    }

    // ---- stage p into LDS; g stays in registers (it IS the coalesced load) ----
    const float4 p4 = ((const float4*)prow)[tid];
    const float4 g4 = ((const float4*)grow)[tid];
    *(float4*)&lds_p[32 + 4 * tid] = p4;
    float gr[CHUNK] = {g4.x, g4.y, g4.z, g4.w};

    // ---- full-row sums ----
    {
        float ap = p4.x + p4.y + p4.z + p4.w;
        float ag = g4.x + g4.y + g4.z + g4.w;
        float app = fmaf(p4.x, p4.x, fmaf(p4.y, p4.y, fmaf(p4.z, p4.z, p4.w * p4.w)));
        float agg = fmaf(g4.x, g4.x, fmaf(g4.y, g4.y, fmaf(g4.z, g4.z, g4.w * g4.w)));
        ap = wave_sum63(ap); ag = wave_sum63(ag);
        app = wave_sum63(app); agg = wave_sum63(agg);
        if (lane == 63) {
            sm.wsums[wid][0] = ap; sm.wsums[wid][1] = ag;
            sm.wsums[wid][2] = app; sm.wsums[wid][3] = agg;
        }
    }

    // ---- edge prefix/suffix sums from GLOBAL (L2-hot): 168 workers ----
    if (tid < 8 * (MAXLAG + 1)) {
        const int aa = tid / (MAXLAG + 1);
        const int k = tid % (MAXLAG + 1);
        const int a = (aa < 4) ? aa : aa + 1;   // {0,1,2,3,5,6,7,8}
        const int m = a % 5;
        const bool useG = (m >= 2);
        const bool bwd = (a >= 5);
        const bool opSq = (m & 1);
        const float* row = useG ? grow : prow;
        float s = 0.f;
        #pragma unroll
        for (int i = 0; i < MAXLAG; ++i) {
            if (i < k) {
                const float x = row[bwd ? (LL - 1 - i) : i];
                s += opSq ? x * x : x;
            }
        }
        sm.edges[a][k] = s;
    }
    __syncthreads();

    const bool isTail = ((tid & 15) == 15);

    // ---- 41 lags: spg only, conflict-free b128 window reads, reg-only math ----
    lag_group<-20, 8>(lds_p, gr, sm, tid, isTail);
    lag_group<-12, 8>(lds_p, gr, sm, tid, isTail);
    lag_group< -4, 8>(lds_p, gr, sm, tid, isTail);
    lag_group<  4, 8>(lds_p, gr, sm, tid, isTail);
    lag_group< 12, 8>(lds_p, gr, sm, tid, isTail);
    lag_group< 20, 1>(lds_p, gr, sm, tid, isTail);
    __syncthreads();

    // ---- wave 0: pcc (register-resident) + argmax + softmax, one phase ----
    if (wid == 0) {
        float v = -3.0f;
        if (lane < NLAGS) {
            const int il = lane;
            const int l = il - MAXLAG;
            const int m = l < 0 ? -l : l;
            const float fn = (float)(LL - m);
            float spg = 0.f;
            #pragma unroll
            for (int r = 0; r < 64; ++r) spg += sm.redPG[r][il];
            float Sp = 0.f, Sg = 0.f, Spp = 0.f, Sgg = 0.f;
            #pragma unroll
            for (int w = 0; w < 16; ++w) {
                Sp += sm.wsums[w][0]; Sg += sm.wsums[w][1];
                Spp += sm.wsums[w][2]; Sgg += sm.wsums[w][3];
            }
            float Spw, Sgw, Sppw, Sggw;
            if (l >= 0) {
                Spw  = Sp  - sm.edges[0][m];
                Sppw = Spp - sm.edges[1][m];
                Sgw  = Sg  - sm.edges[7][m];
                Sggw = Sgg - sm.edges[8][m];
            } else {
                Spw  = Sp  - sm.edges[5][m];
                Sppw = Spp - sm.edges[6][m];
                Sgw  = Sg  - sm.edges[2][m];
                Sggw = Sgg - sm.edges[3][m];
            }
            const float num  = spg - Spw * Sgw / fn;
            const float varp = Sppw - Spw * Spw / fn;
            const float varg = Sggw - Sgw * Sgw / fn;
            const float den2 = fmaxf(varp * varg, 1e-12f);
            v = num / sqrtf(den2);
        }
        float bv = v;
        int bi = lane;
        #pragma unroll
        for (int d = 32; d; d >>= 1) {
            const float ov = __shfl_xor(bv, d, 64);
            const int oi = __shfl_xor(bi, d, 64);
            if (ov > bv || (ov == bv && oi < bi)) { bv = ov; bi = oi; }
        }
        const float zp = __shfl(v, MAXLAG, 64);
        const float e = (lane < NLAGS) ? __expf((v - bv) * (1.0f / TAU)) : 0.0f;
        const float lc = (lane < NLAGS) ? fabsf((float)(lane - MAXLAG)) * (1.0f / MAXLAG) : 0.0f;
        float wsum = e, psum = e * lc;
        #pragma unroll
        for (int d = 32; d; d >>= 1) {
            wsum += __shfl_xor(wsum, d, 64);
            psum += __shfl_xor(psum, d, 64);
        }
        if (lane == 0) {
            sm.best_pcc = bv;
            sm.best_il = bi;
            sm.zero_pcc = zp;
            sm.pen = psum / wsum;
        }
    }
    __syncthreads();

    // ---- L1 for the single best lag: masked pass over own chunk ----
    {
        const int bl = sm.best_il - MAXLAG;
        const int c0 = tid * CHUNK;
        float sab = 0.f;
        #pragma unroll
        for (int k = 0; k < CHUNK; ++k) {
            const int pi = c0 + k + bl;
            const float p = lds_p[32 + pi];  // guards are zero
            const float d = fabsf(p - gr[k]);
            sab += (pi >= 0 && pi < LL) ? d : 0.f;
        }
        sab = row_sum15(sab);
        if (isTail) sm.l1part[tid >> 4] = sab;
    }
    __syncthreads();

    // ---- per-block scalars -> workspace (plain store, no atomics) ----
    if (tid == 0) {
        const int bl = sm.best_il - MAXLAG;
        const int m = bl < 0 ? -bl : bl;
        float sab = 0.f;
        #pragma unroll
        for (int r = 0; r < 64; ++r) sab += sm.l1part[r];
        const float l1 = sab / (float)(LL - m);
        ws[b] = float4{1.0f - sm.best_pcc, l1, 1.0f - sm.zero_pcc, sm.pen};
    }
}

// ---- stage 2: reduce 512 float4 partials -> 4 output scalars ----
__global__ __launch_bounds__(512) void reduce_kernel(const float4* __restrict__ ws,
                                                     float* __restrict__ out) {
    __shared__ float4 part[8];
    const int tid = threadIdx.x;
    const int wid = tid >> 6;
    const int lane = tid & 63;
    const float4 v = ws[tid];
    const float x = wave_sum63(v.x);
    const float y = wave_sum63(v.y);
    const float z = wave_sum63(v.z);
    const float w = wave_sum63(v.w);
    if (lane == 63) part[wid] = float4{x, y, z, w};
    __syncthreads();
    if (tid == 0) {
        float s0 = 0.f, s1 = 0.f, s2 = 0.f, s3 = 0.f;
        #pragma unroll
        for (int i = 0; i < 8; ++i) {
            s0 += part[i].x; s1 += part[i].y; s2 += part[i].z; s3 += part[i].w;
        }
        const float inv = 1.0f / (float)BB;
        out[0] = s0 * inv;
        out[1] = s1 * inv;
        out[2] = s2 * inv;
        out[3] = s3 * inv;
    }
}

extern "C" void kernel_launch(void* const* d_in, const int* in_sizes, int n_in,
                              void* d_out, int out_size, void* d_ws, size_t ws_size,
                              hipStream_t stream) {
    const float* pred = (const float*)d_in[0];
    const float* gt   = (const float*)d_in[1];
    float* out = (float*)d_out;
    float4* ws = (float4*)d_ws;

    lagloss_kernel<<<BB, NT, 0, stream>>>(pred, gt, ws);
    reduce_kernel<<<1, 512, 0, stream>>>(ws, out);
}

// Round 12
// 19.812 us; speedup vs baseline: 1.2332x; 1.2332x over previous
//
#include <hip/hip_runtime.h>
#include <math.h>

#define BB 512
#define LL 4096
#define MAXLAG 20
#define NLAGS 41
#define TAU 0.05f
#define NT 512
#define CHUNK 8

// Padded LDS layout (round-7 proven): element i (i in [-32,4128)) -> ip=i+32,
// fi = ip + 4*(ip>>3) (4 pad floats per 8 data floats, pitch 12 per thread-chunk).
// Thread t owns elements 8t..8t+7: fi = 12t + fo(x), fo(x)=(x+32)+4*((x+32)>>3).
// Lane stride 48 B -> conflict-free ds_read_b128.

// ---- DPP adds ----
template<int CTRL, int RM, int BM, bool BC>
__device__ __forceinline__ float dpp_add(float x) {
    const int t = __builtin_amdgcn_update_dpp(0, __float_as_int(x), CTRL, RM, BM, BC);
    return x + __int_as_float(t);
}
// full 64-lane sum; result in lane 63
__device__ __forceinline__ float wave_sum63(float x) {
    x = dpp_add<0x111, 0xf, 0xf, true >(x);  // row_shr:1
    x = dpp_add<0x112, 0xf, 0xf, true >(x);  // row_shr:2
    x = dpp_add<0x114, 0xf, 0xf, true >(x);  // row_shr:4
    x = dpp_add<0x118, 0xf, 0xf, true >(x);  // row_shr:8
    x = dpp_add<0x142, 0xa, 0xf, false>(x);  // row_bcast:15
    x = dpp_add<0x143, 0xc, 0xf, false>(x);  // row_bcast:31 -> lane63 total
    return x;
}
// 16-lane row sum; result in lane 15 of each row
__device__ __forceinline__ float row_sum15(float x) {
    x = dpp_add<0x111, 0xf, 0xf, true >(x);
    x = dpp_add<0x112, 0xf, 0xf, true >(x);
    x = dpp_add<0x114, 0xf, 0xf, true >(x);
    x = dpp_add<0x118, 0xf, 0xf, true >(x);
    return x;
}
// sum of lanes 0..31; result in lane 31
__device__ __forceinline__ float half_sum31(float x) {
    x = dpp_add<0x111, 0xf, 0xf, true >(x);
    x = dpp_add<0x112, 0xf, 0xf, true >(x);
    x = dpp_add<0x114, 0xf, 0xf, true >(x);
    x = dpp_add<0x118, 0xf, 0xf, true >(x);
    x = dpp_add<0x142, 0xa, 0xf, false>(x);  // row_bcast:15 -> lane31 = lanes0..31
    return x;
}

struct SmemT {
    float redPG[32][NLAGS];       // 32 row-partials (16-lane groups) per lag
    float edges[10][MAXLAG + 1];  // 0:prefP 1:prefPP 2:prefG 3:prefGG (4 unused)
                                  // 5:sufP  6:sufPP  7:sufG  8:sufGG  (9 unused)
    float wsums[8][4];
    float pcc_s[NLAGS];
    float l1part[32];
    float best_pcc, zero_pcc, pen;
    int best_il;
};

// one lag group: lags L0 .. L0+G-1 (L0 % 4 == 0); computes only spg
template<int L0, int G>
__device__ __forceinline__ void lag_group(const float* __restrict__ lds_p,
                                          const float (&gr)[CHUNK],
                                          SmemT& sm, int tid, bool isTail) {
    constexpr int NW4 = (G + CHUNK + 2) / 4;   // G=8 -> 4 float4, G=1 -> 2
    float pw[NW4 * 4];
    const int pbase = 12 * tid;
    #pragma unroll
    for (int k = 0; k < NW4; ++k) {
        const int x32 = L0 + 4 * k + 32;       // >= 12, mult of 4
        const int fo = x32 + 4 * (x32 >> 3);
        const float4 w = *(const float4*)&lds_p[pbase + fo];
        pw[4 * k + 0] = w.x; pw[4 * k + 1] = w.y;
        pw[4 * k + 2] = w.z; pw[4 * k + 3] = w.w;
    }
    #pragma unroll
    for (int dl = 0; dl < G; ++dl) {
        float s0 = 0.f, s1 = 0.f;
        #pragma unroll
        for (int k = 0; k < CHUNK; k += 2) {
            s0 = fmaf(pw[dl + k],     gr[k],     s0);
            s1 = fmaf(pw[dl + k + 1], gr[k + 1], s1);
        }
        const float spg = row_sum15(s0 + s1);
        if (isTail) sm.redPG[tid >> 4][L0 + MAXLAG + dl] = spg;
    }
}

__global__ __launch_bounds__(NT, 4) void lagloss_kernel(const float* __restrict__ pred,
                                                        const float* __restrict__ gt,
                                                        float4* __restrict__ ws) {
    __shared__ float lds_p[6240];
    __shared__ SmemT sm;

    const int b = blockIdx.x;
    const int tid = threadIdx.x;
    const int wid = tid >> 6;
    const int lane = tid & 63;
    const float* __restrict__ prow = pred + (size_t)b * LL;
    const float* __restrict__ grow = gt + (size_t)b * LL;

    // ---- zero the p pads: ip in [0,32) and [4128,4160) ----
    if (tid < 16) {
        const int m = tid & 7;
        const int ip = ((tid & 8) ? 4128 : 0) + 4 * m;
        const int fi = ip + 4 * (ip >> 3);
        *(float4*)&lds_p[fi] = float4{0.f, 0.f, 0.f, 0.f};
    }

    // ---- stage own chunk: p -> padded LDS, g -> registers; fused row sums ----
    const float4 pa = ((const float4*)prow)[2 * tid];
    const float4 pb = ((const float4*)prow)[2 * tid + 1];
    const float4 ga = ((const float4*)grow)[2 * tid];
    const float4 gb = ((const float4*)grow)[2 * tid + 1];
    const int pbase = 12 * tid;
    *(float4*)&lds_p[pbase + 48] = pa;   // fo(0)=48
    *(float4*)&lds_p[pbase + 52] = pb;   // fo(4)=52
    float gr[CHUNK] = {ga.x, ga.y, ga.z, ga.w, gb.x, gb.y, gb.z, gb.w};
    {
        float ap = (pa.x + pa.y) + (pa.z + pa.w) + (pb.x + pb.y) + (pb.z + pb.w);
        float ag = (ga.x + ga.y) + (ga.z + ga.w) + (gb.x + gb.y) + (gb.z + gb.w);
        float app = fmaf(pa.x, pa.x, fmaf(pa.y, pa.y, fmaf(pa.z, pa.z, pa.w * pa.w)));
        app = fmaf(pb.x, pb.x, fmaf(pb.y, pb.y, fmaf(pb.z, pb.z, fmaf(pb.w, pb.w, app))));
        float agg = fmaf(ga.x, ga.x, fmaf(ga.y, ga.y, fmaf(ga.z, ga.z, ga.w * ga.w)));
        agg = fmaf(gb.x, gb.x, fmaf(gb.y, gb.y, fmaf(gb.z, gb.z, fmaf(gb.w, gb.w, agg))));
        ap = wave_sum63(ap); ag = wave_sum63(ag);
        app = wave_sum63(app); agg = wave_sum63(agg);
        if (lane == 63) {
            sm.wsums[wid][0] = ap; sm.wsums[wid][1] = ag;
            sm.wsums[wid][2] = app; sm.wsums[wid][3] = agg;
        }
    }

    // ---- edge prefix/suffix sums from GLOBAL (L1/L2-hot), pre-barrier ----
    if (tid < 8 * (MAXLAG + 1)) {
        const int aa = tid / (MAXLAG + 1);
        const int k = tid % (MAXLAG + 1);
        const int a = (aa < 4) ? aa : aa + 1;   // {0,1,2,3,5,6,7,8}
        const int m = a % 5;
        const bool useG = (m >= 2);
        const bool bwd = (a >= 5);
        const bool opSq = (m & 1);
        const float* row = useG ? grow : prow;
        float s = 0.f;
        #pragma unroll
        for (int i = 0; i < MAXLAG; ++i) {
            if (i < k) {
                const float x = row[bwd ? (LL - 1 - i) : i];
                s += opSq ? x * x : x;
            }
        }
        sm.edges[a][k] = s;
    }
    __syncthreads();

    const bool isTail = ((tid & 15) == 15);

    // ---- 41 lags: spg only, conflict-free b128 window reads, reg-only math ----
    lag_group<-20, 8>(lds_p, gr, sm, tid, isTail);
    lag_group<-12, 8>(lds_p, gr, sm, tid, isTail);
    lag_group< -4, 8>(lds_p, gr, sm, tid, isTail);
    lag_group<  4, 8>(lds_p, gr, sm, tid, isTail);
    lag_group< 12, 8>(lds_p, gr, sm, tid, isTail);
    lag_group< 20, 1>(lds_p, gr, sm, tid, isTail);
    __syncthreads();

    // ---- pcc assembly parallel across 8 waves: wave w takes lags w, w+8, ... ----
    {
        float Sp = 0.f, Sg = 0.f, Spp = 0.f, Sgg = 0.f;
        #pragma unroll
        for (int w = 0; w < 8; ++w) {
            Sp += sm.wsums[w][0]; Sg += sm.wsums[w][1];
            Spp += sm.wsums[w][2]; Sgg += sm.wsums[w][3];
        }
        #pragma unroll
        for (int j = 0; j < 6; ++j) {
            const int il = wid + 8 * j;
            if (il < NLAGS) {
                const float v = (lane < 32) ? sm.redPG[lane][il] : 0.0f;
                const float spg = half_sum31(v);
                if (lane == 31) {
                    const int l = il - MAXLAG;
                    const int m = l < 0 ? -l : l;
                    const float fn = (float)(LL - m);
                    float Spw, Sgw, Sppw, Sggw;
                    if (l >= 0) {
                        Spw  = Sp  - sm.edges[0][m];
                        Sppw = Spp - sm.edges[1][m];
                        Sgw  = Sg  - sm.edges[7][m];
                        Sggw = Sgg - sm.edges[8][m];
                    } else {
                        Spw  = Sp  - sm.edges[5][m];
                        Sppw = Spp - sm.edges[6][m];
                        Sgw  = Sg  - sm.edges[2][m];
                        Sggw = Sgg - sm.edges[3][m];
                    }
                    const float num  = spg - Spw * Sgw / fn;
                    const float varp = Sppw - Spw * Spw / fn;
                    const float varg = Sggw - Sgw * Sgw / fn;
                    const float den2 = fmaxf(varp * varg, 1e-12f);
                    sm.pcc_s[il] = num / sqrtf(den2);
                }
            }
        }
    }
    __syncthreads();

    // ---- wave 0: argmax + softmax penalty, lane-parallel ----
    if (wid == 0) {
        const float v = (lane < NLAGS) ? sm.pcc_s[lane] : -3.0f;
        float bv = v;
        int bi = lane;
        #pragma unroll
        for (int d = 32; d; d >>= 1) {
            const float ov = __shfl_xor(bv, d, 64);
            const int oi = __shfl_xor(bi, d, 64);
            if (ov > bv || (ov == bv && oi < bi)) { bv = ov; bi = oi; }
        }
        const float zp = __shfl(v, MAXLAG, 64);
        const float e = (lane < NLAGS) ? __expf((v - bv) * (1.0f / TAU)) : 0.0f;
        const float lc = (lane < NLAGS) ? fabsf((float)(lane - MAXLAG)) * (1.0f / MAXLAG) : 0.0f;
        float wsum = e, psum = e * lc;
        #pragma unroll
        for (int d = 32; d; d >>= 1) {
            wsum += __shfl_xor(wsum, d, 64);
            psum += __shfl_xor(psum, d, 64);
        }
        if (lane == 0) {
            sm.best_pcc = bv;
            sm.best_il = bi;
            sm.zero_pcc = zp;
            sm.pen = psum / wsum;
        }
    }
    __syncthreads();

    // ---- L1 for the single best lag: masked pass over own chunk ----
    {
        const int bl = sm.best_il - MAXLAG;
        const int c0 = tid * CHUNK;
        float sab = 0.f;
        #pragma unroll
        for (int k = 0; k < CHUNK; ++k) {
            const int pi = c0 + k + bl;
            const int ip = pi + 32;
            const float p = lds_p[ip + 4 * (ip >> 3)];  // pads are zero
            const float d = fabsf(p - gr[k]);
            sab += (pi >= 0 && pi < LL) ? d : 0.f;
        }
        sab = row_sum15(sab);
        if (isTail) sm.l1part[tid >> 4] = sab;
    }
    __syncthreads();

    // ---- per-block scalars -> workspace (plain store, no atomics) ----
    if (tid == 0) {
        const int bl = sm.best_il - MAXLAG;
        const int m = bl < 0 ? -bl : bl;
        float sab = 0.f;
        #pragma unroll
        for (int r = 0; r < 32; ++r) sab += sm.l1part[r];
        const float l1 = sab / (float)(LL - m);
        ws[b] = float4{1.0f - sm.best_pcc, l1, 1.0f - sm.zero_pcc, sm.pen};
    }
}

// ---- stage 2: reduce 512 float4 partials -> 4 output scalars ----
__global__ __launch_bounds__(512) void reduce_kernel(const float4* __restrict__ ws,
                                                     float* __restrict__ out) {
    __shared__ float4 part[8];
    const int tid = threadIdx.x;
    const int wid = tid >> 6;
    const int lane = tid & 63;
    const float4 v = ws[tid];
    const float x = wave_sum63(v.x);
    const float y = wave_sum63(v.y);
    const float z = wave_sum63(v.z);
    const float w = wave_sum63(v.w);
    if (lane == 63) part[wid] = float4{x, y, z, w};
    __syncthreads();
    if (tid == 0) {
        float s0 = 0.f, s1 = 0.f, s2 = 0.f, s3 = 0.f;
        #pragma unroll
        for (int i = 0; i < 8; ++i) {
            s0 += part[i].x; s1 += part[i].y; s2 += part[i].z; s3 += part[i].w;
        }
        const float inv = 1.0f / (float)BB;
        out[0] = s0 * inv;
        out[1] = s1 * inv;
        out[2] = s2 * inv;
        out[3] = s3 * inv;
    }
}

extern "C" void kernel_launch(void* const* d_in, const int* in_sizes, int n_in,
                              void* d_out, int out_size, void* d_ws, size_t ws_size,
                              hipStream_t stream) {
    const float* pred = (const float*)d_in[0];
    const float* gt   = (const float*)d_in[1];
    float* out = (float*)d_out;
    float4* ws = (float4*)d_ws;

    lagloss_kernel<<<BB, NT, 0, stream>>>(pred, gt, ws);
    reduce_kernel<<<1, 512, 0, stream>>>(ws, out);
}